// Round 11
// baseline (136.859 us; speedup 1.0000x reference)
//
#include <hip/hip_runtime.h>
#include <math.h>

#define D_MODEL 1024
#define N_HEADS 16
#define N_PHASE 128
#define HEAD_DIM 64
#define B_SZ 2
#define L_SEQ 2048
#define QK_SCALE 0.35355339059327373f   // 1/sqrt(8)
#define LN_EPS 1e-5f
#define POS_COEF 0.07195578415606394f   // ln(10000)/128
#define INV_2PI 0.15915494309189535f

typedef __attribute__((ext_vector_type(8))) short bf16x8;
typedef __attribute__((ext_vector_type(4))) short s16x4;
typedef __attribute__((ext_vector_type(4))) float f32x4;

// ---------------------------------------------------------------- helpers
__device__ __forceinline__ float wave_reduce_sum(float v) {
#pragma unroll
  for (int off = 32; off > 0; off >>= 1) v += __shfl_xor(v, off);
  return v;
}
// f32 -> bf16 (RNE)
__device__ __forceinline__ unsigned short f2bf(float x) {
  unsigned u = __float_as_uint(x);
  u += 0x7fffu + ((u >> 16) & 1u);
  return (unsigned short)(u >> 16);
}
__device__ __forceinline__ void gload16(const short* g, short* l) {
  __builtin_amdgcn_global_load_lds(
      (const __attribute__((address_space(1))) void*)g,
      (__attribute__((address_space(3))) void*)l, 16, 0, 0);
}
// hw sin/cos with explicit range reduction (v_sin/v_cos take REVOLUTIONS,
// limited domain -> reduce to [-0.5, 0.5] rev with rndne first)
__device__ __forceinline__ void fast_sincos(float ang, float* s, float* c) {
  float rev = ang * INV_2PI;
  rev = rev - rintf(rev);
  *c = __builtin_amdgcn_cosf(rev);
  *s = __builtin_amdgcn_sinf(rev);
}

// ---------------------------------------------------------------- merged converts
// seg0: x_imag -> xi_bf + f32 passthrough to outi; x_real -> xr_bf
// seg1: Wq/Wk -> bf16     seg2: Wv/Wo -> bf16
#define NX4 ((B_SZ * L_SEQ * D_MODEL) / 4)          // 1048576 -> 4096 blocks
#define NWP4 ((N_PHASE * D_MODEL) / 4)              // 32768   -> 128 blocks
#define NW4 ((D_MODEL * D_MODEL) / 4)               // 262144  -> 1024 blocks
__device__ __forceinline__ s16x4 cvt4(float4 v) {
  s16x4 o;
  o[0] = (short)f2bf(v.x);
  o[1] = (short)f2bf(v.y);
  o[2] = (short)f2bf(v.z);
  o[3] = (short)f2bf(v.w);
  return o;
}
__global__ __launch_bounds__(256) void cvtall_kernel(
    const float* __restrict__ x_real, const float* __restrict__ x_imag,
    const float* __restrict__ Wq, const float* __restrict__ Wk,
    const float* __restrict__ Wv, const float* __restrict__ Wo,
    short* __restrict__ xr_bf, short* __restrict__ xi_bf,
    short* __restrict__ Wq_bf, short* __restrict__ Wk_bf,
    short* __restrict__ Wv_bf, short* __restrict__ Wo_bf,
    float* __restrict__ outi) {
  const int i = blockIdx.x * 256 + threadIdx.x;
  if (i < NX4) {
    const float4 vi = ((const float4*)x_imag)[i];
    ((float4*)outi)[i] = vi;
    ((s16x4*)xi_bf)[i] = cvt4(vi);
    ((s16x4*)xr_bf)[i] = cvt4(((const float4*)x_real)[i]);
  } else if (i < NX4 + NWP4) {
    const int j = i - NX4;
    ((s16x4*)Wq_bf)[j] = cvt4(((const float4*)Wq)[j]);
    ((s16x4*)Wk_bf)[j] = cvt4(((const float4*)Wk)[j]);
  } else if (i < NX4 + NWP4 + NW4) {
    const int j = i - NX4 - NWP4;
    ((s16x4*)Wv_bf)[j] = cvt4(((const float4*)Wv)[j]);
    ((s16x4*)Wo_bf)[j] = cvt4(((const float4*)Wo)[j]);
  }
}

// ---------------------------------------------------------------- GEMM core
// 128x64 tile, BK=32, 4 waves (2x2). Wave tile 64x32, frags af[4] x bfr[2].
// LDS chunk-XOR swizzle (involution) applied on the GLOBAL source
// (gload_lds dest is linear) and on the LDS read side.
__device__ __forceinline__ void gemm_core(const short* __restrict__ A,
                                          const short* __restrict__ Bm, int K,
                                          int mBase, int nBase,
                                          f32x4 acc[4][2], short* As,
                                          short* Bs) {
  const int tid = threadIdx.x;
  const int wv = tid >> 6, ln = tid & 63;
  const int wr = wv >> 1, wc = wv & 1;
  const int fr = ln & 15, fc = ln >> 4;
  const int cg = (ln & 3) ^ ((ln >> 3) & 3);  // swizzled source chunk
  const short* ga = A + (size_t)(mBase + wv * 16 + (ln >> 2)) * K + cg * 8;
  const short* gb = Bm + (size_t)(nBase + wv * 16 + (ln >> 2)) * K + cg * 8;
  short* la = As + wv * 512;
  short* lb = Bs + wv * 512;
  const int ra = (wr * 64 + fr) * 32 + (fc ^ ((fr >> 1) & 3)) * 8;
  const int rb = (wc * 32 + fr) * 32 + (fc ^ ((fr >> 1) & 3)) * 8;

  for (int k0 = 0; k0 < K; k0 += 32) {
    __syncthreads();
    gload16(ga + k0, la);
    gload16(ga + k0 + (size_t)64 * K, la + 64 * 32);
    gload16(gb + k0, lb);
    __syncthreads();

    bf16x8 af[4], bfr[2];
#pragma unroll
    for (int mi = 0; mi < 4; ++mi) af[mi] = *(const bf16x8*)&As[ra + mi * 512];
#pragma unroll
    for (int ni = 0; ni < 2; ++ni) bfr[ni] = *(const bf16x8*)&Bs[rb + ni * 512];

#pragma unroll
    for (int mi = 0; mi < 4; ++mi)
#pragma unroll
      for (int ni = 0; ni < 2; ++ni)
        acc[mi][ni] = __builtin_amdgcn_mfma_f32_16x16x32_bf16(
            af[mi], bfr[ni], acc[mi][ni], 0, 0, 0);
  }
}

// ---------------------------------------------------------------- fused QKV projections
// grid (M/128, 20): y in [0,2) -> Q phase, [2,4) -> K phase, [4,20) -> V GEMM
__global__ __launch_bounds__(256) void qkv_kernel(
    const short* __restrict__ xi, const short* __restrict__ xr,
    const short* __restrict__ WqB, const short* __restrict__ WkB,
    const short* __restrict__ WvB, const float* __restrict__ bq,
    const float* __restrict__ bk, short* __restrict__ qf,
    short* __restrict__ kf, short* __restrict__ Vt) {
  __shared__ short As[128 * 32];
  __shared__ short Bs[64 * 32];
  const int y = blockIdx.y;
  const int mBase = blockIdx.x * 128;
  const short* A;
  const short* Bm;
  int nBase;
  if (y < 4) {
    A = xi;
    Bm = (y < 2) ? WqB : WkB;
    nBase = (y & 1) * 64;
  } else {
    A = xr;
    Bm = WvB;
    nBase = (y - 4) * 64;
  }

  f32x4 acc[4][2];
#pragma unroll
  for (int i = 0; i < 4; ++i)
#pragma unroll
    for (int j = 0; j < 2; ++j) acc[i][j] = (f32x4){0.f, 0.f, 0.f, 0.f};
  gemm_core(A, Bm, D_MODEL, mBase, nBase, acc, As, Bs);

  const int ln = threadIdx.x & 63, wv = threadIdx.x >> 6;
  const int wr = wv >> 1, wc = wv & 1;
  const int fr = ln & 15, fc = ln >> 4;

  if (y < 4) {
    const float* bias = (y < 2) ? bq : bk;
    short* Cs = (y < 2) ? qf : kf;
    const float fscale = (y < 2) ? QK_SCALE : 1.0f;
#pragma unroll
    for (int mi = 0; mi < 4; ++mi)
#pragma unroll
      for (int ni = 0; ni < 2; ++ni)
#pragma unroll
        for (int r = 0; r < 4; ++r) {
          const int m = mBase + wr * 64 + mi * 16 + fc * 4 + r;
          const int n = nBase + wc * 32 + ni * 16 + fr;
          const int b = m >> 11, l = m & (L_SEQ - 1);
          const float inv_freq = __expf(-(float)(n & ~1) * POS_COEF);
          const float ang = acc[mi][ni][r] + bias[n] + (float)l * inv_freq;
          float sv, cv;
          fast_sincos(ang, &sv, &cv);
          const int h = n >> 3, p = n & 7;
          const size_t base = ((size_t)((b << 4) + h) * L_SEQ + l) * 16;
          Cs[base + p] = (short)f2bf(cv * fscale);
          Cs[base + 8 + p] = (short)f2bf(sv * fscale);
        }
  } else {
    // Vt (B,H,64,L) with j-rows PI-permuted within each 32-block:
    // position [g1 g0 e2 e1 e0] holds V row [e2 g1 g0 e1 e0]  (top-3-bit
    // rotation; low 2 bits untouched -> 4-wide store stays contiguous).
    // This makes attention's PV B-frag purely lane-local (no LDS/exchange).
#pragma unroll
    for (int mi = 0; mi < 4; ++mi)
#pragma unroll
      for (int ni = 0; ni < 2; ++ni) {
        const int n = nBase + wc * 32 + ni * 16 + fr;
        const int m = mBase + wr * 64 + mi * 16 + fc * 4;
        const int b = m >> 11, l = m & (L_SEQ - 1);
        const int t = (l >> 2) & 7;
        const int tp = ((t << 1) & 6) | (t >> 2);
        const int lpos = (l & ~31) | (tp << 2);
        const int h = n >> 6, d = n & 63;
        s16x4 pk;
#pragma unroll
        for (int r = 0; r < 4; ++r) pk[r] = (short)f2bf(acc[mi][ni][r]);
        *(s16x4*)&Vt[((size_t)((b << 4) + h) * 64 + d) * L_SEQ + lpos] = pk;
      }
  }
}

// ---------------------------------------------------------------- O GEMM (+residual)
__global__ __launch_bounds__(256) void ogemm_kernel(
    const short* __restrict__ A, const short* __restrict__ Bm,
    const float* __restrict__ resid, float* __restrict__ Cf) {
  __shared__ short As[128 * 32];
  __shared__ short Bs[64 * 32];
  const int mBase = blockIdx.x * 128, nBase = blockIdx.y * 64;

  f32x4 acc[4][2];
#pragma unroll
  for (int i = 0; i < 4; ++i)
#pragma unroll
    for (int j = 0; j < 2; ++j) acc[i][j] = (f32x4){0.f, 0.f, 0.f, 0.f};
  gemm_core(A, Bm, D_MODEL, mBase, nBase, acc, As, Bs);

  const int ln = threadIdx.x & 63, wv = threadIdx.x >> 6;
  const int wr = wv >> 1, wc = wv & 1;
  const int fr = ln & 15, fc = ln >> 4;
#pragma unroll
  for (int mi = 0; mi < 4; ++mi)
#pragma unroll
    for (int ni = 0; ni < 2; ++ni)
#pragma unroll
      for (int r = 0; r < 4; ++r) {
        const int m = mBase + wr * 64 + mi * 16 + fc * 4 + r;
        const int n = nBase + wc * 32 + ni * 16 + fr;
        const size_t idx = (size_t)m * D_MODEL + n;
        Cf[idx] = acc[mi][ni][r] + resid[idx];
      }
}

// ---------------------------------------------------------------- MFMA attention
// Intra-block flash-split over j: grid (B*H, 128), block = one 16-row q-group
// (qg = 127 - y, longest-first), 4 waves. Wave w processes j-tiles t = w,
// w+4, w+8, ... accumulating PRIVATE partial o/lsum (pure sums -- no online
// max needed since scores are bounded by 8*SCALE); a 17 KB LDS combine sums
// the 4 partials and normalizes. Longest serial chain: 32 -> 8 tiles; grid
// 4096 blocks -> ~28 waves/CU resident for latency hiding.
__global__ __launch_bounds__(256) void attn_mfma_kernel(
    const short* __restrict__ qf, const short* __restrict__ kf,
    const short* __restrict__ Vt, short* __restrict__ ao) {
  const int bh = blockIdx.x;
  const int qg = 127 - (int)blockIdx.y;  // longest blocks dispatch first
  const int tid = threadIdx.x;
  const int w = tid >> 6;
  const int lane = tid & 63;
  const int g = lane >> 4;
  const int q16 = lane & 15;
  const int qglob = qg * 16 + q16;
  const int ntiles = (qg >> 2) + 1;

  __shared__ float ol[4][16][68];  // stride 68: 2-way bank aliasing only
  __shared__ float ll[4][16];

  const short* qf_h = qf + (size_t)bh * L_SEQ * 16;
  const short* kf_h = kf + (size_t)bh * L_SEQ * 16;
  const short* Vt_h = Vt + (size_t)bh * 64 * L_SEQ;
  const int b = bh >> 4, h = bh & 15;

  bf16x8 qfrag = {0, 0, 0, 0, 0, 0, 0, 0};
  if (g < 2) qfrag = *(const bf16x8*)(qf_h + (size_t)qglob * 16 + g * 8);

  f32x4 o[4];
#pragma unroll
  for (int dc = 0; dc < 4; ++dc) o[dc] = (f32x4){0.f, 0.f, 0.f, 0.f};
  float lsum = 0.f;

#pragma unroll 1
  for (int t = w; t < ntiles; t += 4) {
    const int j0 = t << 6;

    // V for this tile (PI-permuted rows -> lane-local PV pairing)
    bf16x8 vf0[4], vf1[4];
#pragma unroll
    for (int dc = 0; dc < 4; ++dc)
      vf0[dc] = *(const bf16x8*)(Vt_h + (size_t)(dc * 16 + q16) * L_SEQ + j0 +
                                 g * 8);

    // K fragments for this tile
    bf16x8 kfr[4];
#pragma unroll
    for (int jt = 0; jt < 4; ++jt) {
      kfr[jt] = (bf16x8){0, 0, 0, 0, 0, 0, 0, 0};
      if (g < 2)
        kfr[jt] =
            *(const bf16x8*)(kf_h + (size_t)(j0 + jt * 16 + q16) * 16 + g * 8);
    }

    // QK^T (swapped): lane holds q=q16, j = j0 + jt*16 + g*4 + r
    f32x4 s[4];
#pragma unroll
    for (int jt = 0; jt < 4; ++jt)
      s[jt] = __builtin_amdgcn_mfma_f32_16x16x32_bf16(
          kfr[jt], qfrag, (f32x4){0.f, 0.f, 0.f, 0.f}, 0, 0, 0);

#pragma unroll
    for (int dc = 0; dc < 4; ++dc)
      vf1[dc] = *(const bf16x8*)(Vt_h + (size_t)(dc * 16 + q16) * L_SEQ + j0 +
                                 32 + g * 8);

    // causal mask (diagonal tile only)
    if (t == ntiles - 1) {
#pragma unroll
      for (int jt = 0; jt < 4; ++jt)
#pragma unroll
        for (int r = 0; r < 4; ++r)
          if (j0 + jt * 16 + g * 4 + r > qglob) s[jt][r] = -INFINITY;
    }

    // exp + per-lane partial sum (P stays in registers)
    float ex[4][4];
#pragma unroll
    for (int jt = 0; jt < 4; ++jt)
#pragma unroll
      for (int r = 0; r < 4; ++r) {
        ex[jt][r] = __expf(s[jt][r]);
        lsum += ex[jt][r];
      }

    // PV: B-frag slot e -> (jt = 2c + (e>>2), r = e&3), all lane-local
#pragma unroll
    for (int c = 0; c < 2; ++c) {
      union {
        unsigned u[4];
        bf16x8 v;
      } pb;
#pragma unroll
      for (int hw = 0; hw < 2; ++hw) {
        pb.u[hw * 2 + 0] = (unsigned)f2bf(ex[2 * c + hw][0]) |
                           ((unsigned)f2bf(ex[2 * c + hw][1]) << 16);
        pb.u[hw * 2 + 1] = (unsigned)f2bf(ex[2 * c + hw][2]) |
                           ((unsigned)f2bf(ex[2 * c + hw][3]) << 16);
      }
      const bf16x8* vfc = c ? vf1 : vf0;
#pragma unroll
      for (int dc = 0; dc < 4; ++dc)
        o[dc] = __builtin_amdgcn_mfma_f32_16x16x32_bf16(vfc[dc], pb.v, o[dc],
                                                        0, 0, 0);
    }
  }

  // ---- combine the 4 waves' partials via LDS
  lsum += __shfl_xor(lsum, 16);
  lsum += __shfl_xor(lsum, 32);
  if (g == 0) ll[w][q16] = lsum;
#pragma unroll
  for (int dc = 0; dc < 4; ++dc)
    *(f32x4*)&ol[w][q16][dc * 16 + g * 4] = o[dc];
  __syncthreads();

  // wave w normalizes d-range [w*16, w*16+16)
  const float lt = (ll[0][q16] + ll[1][q16]) + (ll[2][q16] + ll[3][q16]);
  const float inv = 1.f / lt;
  const int d0 = w * 16 + g * 4;
  s16x4 pk;
#pragma unroll
  for (int r = 0; r < 4; ++r) {
    const float v = ((ol[0][q16][d0 + r] + ol[1][q16][d0 + r]) +
                     (ol[2][q16][d0 + r] + ol[3][q16][d0 + r]));
    pk[r] = (short)f2bf(v * inv);
  }
  short* orow = ao + ((size_t)(b * L_SEQ + qglob)) * D_MODEL + h * 64;
  *(s16x4*)&orow[d0] = pk;
}

// ---------------------------------------------------------------- layernorm (in place)
__global__ __launch_bounds__(256) void ln_kernel(float* __restrict__ io,
                                                 const float* __restrict__ gamma,
                                                 const float* __restrict__ beta) {
  const int row = blockIdx.x;
  float* p = io + (size_t)row * D_MODEL;
  const int tid = threadIdx.x;
  float4 x = ((const float4*)p)[tid];
  float s = x.x + x.y + x.z + x.w;
  float sq = x.x * x.x + x.y * x.y + x.z * x.z + x.w * x.w;
  s = wave_reduce_sum(s);
  sq = wave_reduce_sum(sq);
  __shared__ float ss[4], ssq[4];
  const int w = tid >> 6, lane = tid & 63;
  if (lane == 0) {
    ss[w] = s;
    ssq[w] = sq;
  }
  __syncthreads();
  s = ss[0] + ss[1] + ss[2] + ss[3];
  sq = ssq[0] + ssq[1] + ssq[2] + ssq[3];
  const float mean = s * (1.f / D_MODEL);
  const float var = sq * (1.f / D_MODEL) - mean * mean;
  const float rstd = rsqrtf(var + LN_EPS);
  const float4 g = ((const float4*)gamma)[tid];
  const float4 bt = ((const float4*)beta)[tid];
  float4 y;
  y.x = (x.x - mean) * rstd * g.x + bt.x;
  y.y = (x.y - mean) * rstd * g.y + bt.y;
  y.z = (x.z - mean) * rstd * g.z + bt.z;
  y.w = (x.w - mean) * rstd * g.w + bt.w;
  ((float4*)p)[tid] = y;
}

// ---------------------------------------------------------------- launch
extern "C" void kernel_launch(void* const* d_in, const int* in_sizes, int n_in,
                              void* d_out, int out_size, void* d_ws,
                              size_t ws_size, hipStream_t stream) {
  const float* x_real = (const float*)d_in[0];
  const float* x_imag = (const float*)d_in[1];
  const float* Wq = (const float*)d_in[2];
  const float* bq = (const float*)d_in[3];
  const float* Wk = (const float*)d_in[4];
  const float* bk = (const float*)d_in[5];
  const float* Wv = (const float*)d_in[6];
  const float* Wo = (const float*)d_in[7];
  const float* gamma = (const float*)d_in[8];
  const float* beta = (const float*)d_in[9];

  const size_t n_x = (size_t)B_SZ * L_SEQ * D_MODEL;        // 4M
  const size_t n_w = (size_t)D_MODEL * D_MODEL;             // 1M
  const size_t n_wp = (size_t)N_PHASE * D_MODEL;            // 128K
  const size_t n_qf = (size_t)B_SZ * N_HEADS * L_SEQ * 16;  // 1M

  short* xi_bf = (short*)d_ws;
  short* xr_bf = xi_bf + n_x;  // later reused as ao_bf
  short* Wq_bf = xr_bf + n_x;
  short* Wk_bf = Wq_bf + n_wp;
  short* Wv_bf = Wk_bf + n_wp;
  short* Wo_bf = Wv_bf + n_w;
  short* qf = Wo_bf + n_w;
  short* kf = qf + n_qf;
  short* Vt = kf + n_qf;  // 4M shorts
  short* ao_bf = xr_bf;   // alias: x_real bf16 dead after V GEMM

  float* outr = (float*)d_out;
  float* outi = outr + n_x;

  const dim3 blk(256);
  const int M = B_SZ * L_SEQ;  // 4096

  const int cvt_blocks = (NX4 + NWP4 + NW4 + 255) / 256;
  cvtall_kernel<<<dim3(cvt_blocks), blk, 0, stream>>>(
      x_real, x_imag, Wq, Wk, Wv, Wo, xr_bf, xi_bf, Wq_bf, Wk_bf, Wv_bf,
      Wo_bf, outi);

  qkv_kernel<<<dim3(M / 128, 20), blk, 0, stream>>>(
      xi_bf, xr_bf, Wq_bf, Wk_bf, Wv_bf, bq, bk, qf, kf, Vt);
  attn_mfma_kernel<<<dim3(B_SZ * N_HEADS, 128), blk, 0, stream>>>(qf, kf, Vt,
                                                                  ao_bf);
  ogemm_kernel<<<dim3(M / 128, D_MODEL / 64), blk, 0, stream>>>(
      ao_bf, Wo_bf, x_real, outr);
  ln_kernel<<<dim3(M), blk, 0, stream>>>(outr, gamma, beta);
}

// Round 12
// 100.090 us; speedup vs baseline: 1.3674x; 1.3674x over previous
//
#include <hip/hip_runtime.h>
#include <math.h>

#define D_MODEL 1024
#define N_HEADS 16
#define N_PHASE 128
#define HEAD_DIM 64
#define B_SZ 2
#define L_SEQ 2048
#define QK_SCALE 0.35355339059327373f   // 1/sqrt(8)
#define LN_EPS 1e-5f
#define POS_COEF 0.07195578415606394f   // ln(10000)/128
#define INV_2PI 0.15915494309189535f

typedef __attribute__((ext_vector_type(8))) short bf16x8;
typedef __attribute__((ext_vector_type(4))) short s16x4;
typedef __attribute__((ext_vector_type(4))) float f32x4;

// ---------------------------------------------------------------- helpers
__device__ __forceinline__ float wave_reduce_sum(float v) {
#pragma unroll
  for (int off = 32; off > 0; off >>= 1) v += __shfl_xor(v, off);
  return v;
}
// f32 -> bf16 (RNE)
__device__ __forceinline__ unsigned short f2bf(float x) {
  unsigned u = __float_as_uint(x);
  u += 0x7fffu + ((u >> 16) & 1u);
  return (unsigned short)(u >> 16);
}
__device__ __forceinline__ void gload16(const short* g, short* l) {
  __builtin_amdgcn_global_load_lds(
      (const __attribute__((address_space(1))) void*)g,
      (__attribute__((address_space(3))) void*)l, 16, 0, 0);
}
// hw sin/cos with explicit range reduction (v_sin/v_cos take REVOLUTIONS,
// limited domain -> reduce to [-0.5, 0.5] rev with rndne first)
__device__ __forceinline__ void fast_sincos(float ang, float* s, float* c) {
  float rev = ang * INV_2PI;
  rev = rev - rintf(rev);
  *c = __builtin_amdgcn_cosf(rev);
  *s = __builtin_amdgcn_sinf(rev);
}

// ---------------------------------------------------------------- merged converts
// seg0: x_imag -> xi_bf + f32 passthrough to outi; x_real -> xr_bf
// seg1: Wq/Wk -> bf16     seg2: Wv/Wo -> bf16
#define NX4 ((B_SZ * L_SEQ * D_MODEL) / 4)          // 1048576 -> 4096 blocks
#define NWP4 ((N_PHASE * D_MODEL) / 4)              // 32768   -> 128 blocks
#define NW4 ((D_MODEL * D_MODEL) / 4)               // 262144  -> 1024 blocks
__device__ __forceinline__ s16x4 cvt4(float4 v) {
  s16x4 o;
  o[0] = (short)f2bf(v.x);
  o[1] = (short)f2bf(v.y);
  o[2] = (short)f2bf(v.z);
  o[3] = (short)f2bf(v.w);
  return o;
}
__global__ __launch_bounds__(256) void cvtall_kernel(
    const float* __restrict__ x_real, const float* __restrict__ x_imag,
    const float* __restrict__ Wq, const float* __restrict__ Wk,
    const float* __restrict__ Wv, const float* __restrict__ Wo,
    short* __restrict__ xr_bf, short* __restrict__ xi_bf,
    short* __restrict__ Wq_bf, short* __restrict__ Wk_bf,
    short* __restrict__ Wv_bf, short* __restrict__ Wo_bf,
    float* __restrict__ outi) {
  const int i = blockIdx.x * 256 + threadIdx.x;
  if (i < NX4) {
    const float4 vi = ((const float4*)x_imag)[i];
    ((float4*)outi)[i] = vi;
    ((s16x4*)xi_bf)[i] = cvt4(vi);
    ((s16x4*)xr_bf)[i] = cvt4(((const float4*)x_real)[i]);
  } else if (i < NX4 + NWP4) {
    const int j = i - NX4;
    ((s16x4*)Wq_bf)[j] = cvt4(((const float4*)Wq)[j]);
    ((s16x4*)Wk_bf)[j] = cvt4(((const float4*)Wk)[j]);
  } else if (i < NX4 + NWP4 + NW4) {
    const int j = i - NX4 - NWP4;
    ((s16x4*)Wv_bf)[j] = cvt4(((const float4*)Wv)[j]);
    ((s16x4*)Wo_bf)[j] = cvt4(((const float4*)Wo)[j]);
  }
}

// ---------------------------------------------------------------- GEMM core
// 128x64 tile, BK=32, 4 waves (2x2). Wave tile 64x32, frags af[4] x bfr[2].
// LDS chunk-XOR swizzle (involution) applied on the GLOBAL source
// (gload_lds dest is linear) and on the LDS read side.
__device__ __forceinline__ void gemm_core(const short* __restrict__ A,
                                          const short* __restrict__ Bm, int K,
                                          int mBase, int nBase,
                                          f32x4 acc[4][2], short* As,
                                          short* Bs) {
  const int tid = threadIdx.x;
  const int wv = tid >> 6, ln = tid & 63;
  const int wr = wv >> 1, wc = wv & 1;
  const int fr = ln & 15, fc = ln >> 4;
  const int cg = (ln & 3) ^ ((ln >> 3) & 3);  // swizzled source chunk
  const short* ga = A + (size_t)(mBase + wv * 16 + (ln >> 2)) * K + cg * 8;
  const short* gb = Bm + (size_t)(nBase + wv * 16 + (ln >> 2)) * K + cg * 8;
  short* la = As + wv * 512;
  short* lb = Bs + wv * 512;
  const int ra = (wr * 64 + fr) * 32 + (fc ^ ((fr >> 1) & 3)) * 8;
  const int rb = (wc * 32 + fr) * 32 + (fc ^ ((fr >> 1) & 3)) * 8;

  for (int k0 = 0; k0 < K; k0 += 32) {
    __syncthreads();
    gload16(ga + k0, la);
    gload16(ga + k0 + (size_t)64 * K, la + 64 * 32);
    gload16(gb + k0, lb);
    __syncthreads();

    bf16x8 af[4], bfr[2];
#pragma unroll
    for (int mi = 0; mi < 4; ++mi) af[mi] = *(const bf16x8*)&As[ra + mi * 512];
#pragma unroll
    for (int ni = 0; ni < 2; ++ni) bfr[ni] = *(const bf16x8*)&Bs[rb + ni * 512];

#pragma unroll
    for (int mi = 0; mi < 4; ++mi)
#pragma unroll
      for (int ni = 0; ni < 2; ++ni)
        acc[mi][ni] = __builtin_amdgcn_mfma_f32_16x16x32_bf16(
            af[mi], bfr[ni], acc[mi][ni], 0, 0, 0);
  }
}

// ---------------------------------------------------------------- fused QKV projections
// grid (M/128, 20): y in [0,2) -> Q phase, [2,4) -> K phase, [4,20) -> V GEMM
__global__ __launch_bounds__(256) void qkv_kernel(
    const short* __restrict__ xi, const short* __restrict__ xr,
    const short* __restrict__ WqB, const short* __restrict__ WkB,
    const short* __restrict__ WvB, const float* __restrict__ bq,
    const float* __restrict__ bk, short* __restrict__ qf,
    short* __restrict__ kf, short* __restrict__ Vt) {
  __shared__ short As[128 * 32];
  __shared__ short Bs[64 * 32];
  const int y = blockIdx.y;
  const int mBase = blockIdx.x * 128;
  const short* A;
  const short* Bm;
  int nBase;
  if (y < 4) {
    A = xi;
    Bm = (y < 2) ? WqB : WkB;
    nBase = (y & 1) * 64;
  } else {
    A = xr;
    Bm = WvB;
    nBase = (y - 4) * 64;
  }

  f32x4 acc[4][2];
#pragma unroll
  for (int i = 0; i < 4; ++i)
#pragma unroll
    for (int j = 0; j < 2; ++j) acc[i][j] = (f32x4){0.f, 0.f, 0.f, 0.f};
  gemm_core(A, Bm, D_MODEL, mBase, nBase, acc, As, Bs);

  const int ln = threadIdx.x & 63, wv = threadIdx.x >> 6;
  const int wr = wv >> 1, wc = wv & 1;
  const int fr = ln & 15, fc = ln >> 4;

  if (y < 4) {
    const float* bias = (y < 2) ? bq : bk;
    short* Cs = (y < 2) ? qf : kf;
    const float fscale = (y < 2) ? QK_SCALE : 1.0f;
#pragma unroll
    for (int mi = 0; mi < 4; ++mi)
#pragma unroll
      for (int ni = 0; ni < 2; ++ni)
#pragma unroll
        for (int r = 0; r < 4; ++r) {
          const int m = mBase + wr * 64 + mi * 16 + fc * 4 + r;
          const int n = nBase + wc * 32 + ni * 16 + fr;
          const int b = m >> 11, l = m & (L_SEQ - 1);
          const float inv_freq = __expf(-(float)(n & ~1) * POS_COEF);
          const float ang = acc[mi][ni][r] + bias[n] + (float)l * inv_freq;
          float sv, cv;
          fast_sincos(ang, &sv, &cv);
          const int h = n >> 3, p = n & 7;
          const size_t base = ((size_t)((b << 4) + h) * L_SEQ + l) * 16;
          Cs[base + p] = (short)f2bf(cv * fscale);
          Cs[base + 8 + p] = (short)f2bf(sv * fscale);
        }
  } else {
    // Vt: PI-permuted j-rows (position [g1 g0 e2 e1 e0] holds row
    // [e2 g1 g0 e1 e0]) AND subtile-contiguous layout: each 16d x 32j
    // subtile is 1 KB contiguous, ordered [g][dlo][e] to match lane order,
    // so attention's V load is a fully-coalesced 1 KB wave read.
#pragma unroll
    for (int mi = 0; mi < 4; ++mi)
#pragma unroll
      for (int ni = 0; ni < 2; ++ni) {
        const int n = nBase + wc * 32 + ni * 16 + fr;
        const int m = mBase + wr * 64 + mi * 16 + fc * 4;
        const int b = m >> 11, l = m & (L_SEQ - 1);
        const int t = (l >> 2) & 7;
        const int tp = ((t << 1) & 6) | (t >> 2);
        const int lpos = (l & ~31) | (tp << 2);
        const int h = n >> 6, d = n & 63;
        const int jc = lpos >> 5, jlo = lpos & 31;
        const int gg = jlo >> 3, ee = jlo & 7;  // ee in {0,4}, 4-run within oct
        s16x4 pk;
#pragma unroll
        for (int r = 0; r < 4; ++r) pk[r] = (short)f2bf(acc[mi][ni][r]);
        const size_t off = (size_t)((b << 4) + h) * 64 * L_SEQ +
                           (size_t)(jc * 4 + (d >> 4)) * 512 + gg * 128 +
                           (d & 15) * 8 + ee;
        *(s16x4*)&Vt[off] = pk;
      }
  }
}

// ---------------------------------------------------------------- O GEMM (+residual)
__global__ __launch_bounds__(256) void ogemm_kernel(
    const short* __restrict__ A, const short* __restrict__ Bm,
    const float* __restrict__ resid, float* __restrict__ Cf) {
  __shared__ short As[128 * 32];
  __shared__ short Bs[64 * 32];
  const int mBase = blockIdx.x * 128, nBase = blockIdx.y * 64;

  f32x4 acc[4][2];
#pragma unroll
  for (int i = 0; i < 4; ++i)
#pragma unroll
    for (int j = 0; j < 2; ++j) acc[i][j] = (f32x4){0.f, 0.f, 0.f, 0.f};
  gemm_core(A, Bm, D_MODEL, mBase, nBase, acc, As, Bs);

  const int ln = threadIdx.x & 63, wv = threadIdx.x >> 6;
  const int wr = wv >> 1, wc = wv & 1;
  const int fr = ln & 15, fc = ln >> 4;
#pragma unroll
  for (int mi = 0; mi < 4; ++mi)
#pragma unroll
    for (int ni = 0; ni < 2; ++ni)
#pragma unroll
      for (int r = 0; r < 4; ++r) {
        const int m = mBase + wr * 64 + mi * 16 + fc * 4 + r;
        const int n = nBase + wc * 32 + ni * 16 + fr;
        const size_t idx = (size_t)m * D_MODEL + n;
        Cf[idx] = acc[mi][ni][r] + resid[idx];
      }
}

// ---------------------------------------------------------------- MFMA attention
// Intra-block flash-split over j: grid (B*H, 128), block = one 16-row q-group
// (qg = 127 - y, longest-first), 4 waves; wave w does tiles t = w, w+4, ...
// with private partial o/lsum (bounded scores -> pure-sum combine), LDS
// combine at the end. V loads are 1 KB fully-coalesced wave reads from the
// subtile-contiguous Vt (the round-11 16-way gather was the TA bottleneck).
__global__ __launch_bounds__(256) void attn_mfma_kernel(
    const short* __restrict__ qf, const short* __restrict__ kf,
    const short* __restrict__ Vt, short* __restrict__ ao) {
  const int bh = blockIdx.x;
  const int qg = 127 - (int)blockIdx.y;  // longest blocks dispatch first
  const int tid = threadIdx.x;
  const int w = tid >> 6;
  const int lane = tid & 63;
  const int g = lane >> 4;
  const int q16 = lane & 15;
  const int qglob = qg * 16 + q16;
  const int ntiles = (qg >> 2) + 1;

  __shared__ float ol[4][16][68];  // stride 68: 2-way bank aliasing only
  __shared__ float ll[4][16];

  const short* qf_h = qf + (size_t)bh * L_SEQ * 16;
  const short* kf_h = kf + (size_t)bh * L_SEQ * 16;
  const short* Vt_h = Vt + (size_t)bh * 64 * L_SEQ;
  const int b = bh >> 4, h = bh & 15;

  bf16x8 qfrag = {0, 0, 0, 0, 0, 0, 0, 0};
  if (g < 2) qfrag = *(const bf16x8*)(qf_h + (size_t)qglob * 16 + g * 8);

  f32x4 o[4];
#pragma unroll
  for (int dc = 0; dc < 4; ++dc) o[dc] = (f32x4){0.f, 0.f, 0.f, 0.f};
  float lsum = 0.f;

#pragma unroll 1
  for (int t = w; t < ntiles; t += 4) {
    const int j0 = t << 6;

    // V for this tile: subtile (2t+c)*4+dc, fully-coalesced 1 KB reads
    bf16x8 vf0[4], vf1[4];
#pragma unroll
    for (int dc = 0; dc < 4; ++dc)
      vf0[dc] = *(const bf16x8*)(Vt_h + ((size_t)((2 * t) * 4 + dc) << 9) +
                                 lane * 8);

    // K fragments for this tile
    bf16x8 kfr[4];
#pragma unroll
    for (int jt = 0; jt < 4; ++jt) {
      kfr[jt] = (bf16x8){0, 0, 0, 0, 0, 0, 0, 0};
      if (g < 2)
        kfr[jt] =
            *(const bf16x8*)(kf_h + (size_t)(j0 + jt * 16 + q16) * 16 + g * 8);
    }

    // QK^T (swapped): lane holds q=q16, j = j0 + jt*16 + g*4 + r
    f32x4 s[4];
#pragma unroll
    for (int jt = 0; jt < 4; ++jt)
      s[jt] = __builtin_amdgcn_mfma_f32_16x16x32_bf16(
          kfr[jt], qfrag, (f32x4){0.f, 0.f, 0.f, 0.f}, 0, 0, 0);

#pragma unroll
    for (int dc = 0; dc < 4; ++dc)
      vf1[dc] = *(const bf16x8*)(Vt_h + ((size_t)((2 * t + 1) * 4 + dc) << 9) +
                                 lane * 8);

    // causal mask (diagonal tile only)
    if (t == ntiles - 1) {
#pragma unroll
      for (int jt = 0; jt < 4; ++jt)
#pragma unroll
        for (int r = 0; r < 4; ++r)
          if (j0 + jt * 16 + g * 4 + r > qglob) s[jt][r] = -INFINITY;
    }

    // exp + per-lane partial sum (P stays in registers)
    float ex[4][4];
#pragma unroll
    for (int jt = 0; jt < 4; ++jt)
#pragma unroll
      for (int r = 0; r < 4; ++r) {
        ex[jt][r] = __expf(s[jt][r]);
        lsum += ex[jt][r];
      }

    // PV: B-frag slot e -> (jt = 2c + (e>>2), r = e&3), all lane-local
#pragma unroll
    for (int c = 0; c < 2; ++c) {
      union {
        unsigned u[4];
        bf16x8 v;
      } pb;
#pragma unroll
      for (int hw = 0; hw < 2; ++hw) {
        pb.u[hw * 2 + 0] = (unsigned)f2bf(ex[2 * c + hw][0]) |
                           ((unsigned)f2bf(ex[2 * c + hw][1]) << 16);
        pb.u[hw * 2 + 1] = (unsigned)f2bf(ex[2 * c + hw][2]) |
                           ((unsigned)f2bf(ex[2 * c + hw][3]) << 16);
      }
      const bf16x8* vfc = c ? vf1 : vf0;
#pragma unroll
      for (int dc = 0; dc < 4; ++dc)
        o[dc] = __builtin_amdgcn_mfma_f32_16x16x32_bf16(vfc[dc], pb.v, o[dc],
                                                        0, 0, 0);
    }
  }

  // ---- combine the 4 waves' partials via LDS
  lsum += __shfl_xor(lsum, 16);
  lsum += __shfl_xor(lsum, 32);
  if (g == 0) ll[w][q16] = lsum;
#pragma unroll
  for (int dc = 0; dc < 4; ++dc)
    *(f32x4*)&ol[w][q16][dc * 16 + g * 4] = o[dc];
  __syncthreads();

  // wave w normalizes d-range [w*16, w*16+16)
  const float lt = (ll[0][q16] + ll[1][q16]) + (ll[2][q16] + ll[3][q16]);
  const float inv = 1.f / lt;
  const int d0 = w * 16 + g * 4;
  s16x4 pk;
#pragma unroll
  for (int r = 0; r < 4; ++r) {
    const float v = ((ol[0][q16][d0 + r] + ol[1][q16][d0 + r]) +
                     (ol[2][q16][d0 + r] + ol[3][q16][d0 + r]));
    pk[r] = (short)f2bf(v * inv);
  }
  short* orow = ao + ((size_t)(b * L_SEQ + qglob)) * D_MODEL + h * 64;
  *(s16x4*)&orow[d0] = pk;
}

// ---------------------------------------------------------------- layernorm (in place)
__global__ __launch_bounds__(256) void ln_kernel(float* __restrict__ io,
                                                 const float* __restrict__ gamma,
                                                 const float* __restrict__ beta) {
  const int row = blockIdx.x;
  float* p = io + (size_t)row * D_MODEL;
  const int tid = threadIdx.x;
  float4 x = ((const float4*)p)[tid];
  float s = x.x + x.y + x.z + x.w;
  float sq = x.x * x.x + x.y * x.y + x.z * x.z + x.w * x.w;
  s = wave_reduce_sum(s);
  sq = wave_reduce_sum(sq);
  __shared__ float ss[4], ssq[4];
  const int w = tid >> 6, lane = tid & 63;
  if (lane == 0) {
    ss[w] = s;
    ssq[w] = sq;
  }
  __syncthreads();
  s = ss[0] + ss[1] + ss[2] + ss[3];
  sq = ssq[0] + ssq[1] + ssq[2] + ssq[3];
  const float mean = s * (1.f / D_MODEL);
  const float var = sq * (1.f / D_MODEL) - mean * mean;
  const float rstd = rsqrtf(var + LN_EPS);
  const float4 g = ((const float4*)gamma)[tid];
  const float4 bt = ((const float4*)beta)[tid];
  float4 y;
  y.x = (x.x - mean) * rstd * g.x + bt.x;
  y.y = (x.y - mean) * rstd * g.y + bt.y;
  y.z = (x.z - mean) * rstd * g.z + bt.z;
  y.w = (x.w - mean) * rstd * g.w + bt.w;
  ((float4*)p)[tid] = y;
}

// ---------------------------------------------------------------- launch
extern "C" void kernel_launch(void* const* d_in, const int* in_sizes, int n_in,
                              void* d_out, int out_size, void* d_ws,
                              size_t ws_size, hipStream_t stream) {
  const float* x_real = (const float*)d_in[0];
  const float* x_imag = (const float*)d_in[1];
  const float* Wq = (const float*)d_in[2];
  const float* bq = (const float*)d_in[3];
  const float* Wk = (const float*)d_in[4];
  const float* bk = (const float*)d_in[5];
  const float* Wv = (const float*)d_in[6];
  const float* Wo = (const float*)d_in[7];
  const float* gamma = (const float*)d_in[8];
  const float* beta = (const float*)d_in[9];

  const size_t n_x = (size_t)B_SZ * L_SEQ * D_MODEL;        // 4M
  const size_t n_w = (size_t)D_MODEL * D_MODEL;             // 1M
  const size_t n_wp = (size_t)N_PHASE * D_MODEL;            // 128K
  const size_t n_qf = (size_t)B_SZ * N_HEADS * L_SEQ * 16;  // 1M

  short* xi_bf = (short*)d_ws;
  short* xr_bf = xi_bf + n_x;  // later reused as ao_bf
  short* Wq_bf = xr_bf + n_x;
  short* Wk_bf = Wq_bf + n_wp;
  short* Wv_bf = Wk_bf + n_wp;
  short* Wo_bf = Wv_bf + n_w;
  short* qf = Wo_bf + n_w;
  short* kf = qf + n_qf;
  short* Vt = kf + n_qf;  // 4M shorts
  short* ao_bf = xr_bf;   // alias: x_real bf16 dead after V GEMM

  float* outr = (float*)d_out;
  float* outi = outr + n_x;

  const dim3 blk(256);
  const int M = B_SZ * L_SEQ;  // 4096

  const int cvt_blocks = (NX4 + NWP4 + NW4 + 255) / 256;
  cvtall_kernel<<<dim3(cvt_blocks), blk, 0, stream>>>(
      x_real, x_imag, Wq, Wk, Wv, Wo, xr_bf, xi_bf, Wq_bf, Wk_bf, Wv_bf,
      Wo_bf, outi);

  qkv_kernel<<<dim3(M / 128, 20), blk, 0, stream>>>(
      xi_bf, xr_bf, Wq_bf, Wk_bf, Wv_bf, bq, bk, qf, kf, Vt);
  attn_mfma_kernel<<<dim3(B_SZ * N_HEADS, 128), blk, 0, stream>>>(qf, kf, Vt,
                                                                  ao_bf);
  ogemm_kernel<<<dim3(M / 128, D_MODEL / 64), blk, 0, stream>>>(
      ao_bf, Wo_bf, x_real, outr);
  ln_kernel<<<dim3(M), blk, 0, stream>>>(outr, gamma, beta);
}